// Round 16
// baseline (183.385 us; speedup 1.0000x reference)
//
#include <hip/hip_runtime.h>
#include <hip/hip_bf16.h>

#define EMBED 1024
#define WINDOW 512
#define NROWS 16384  // 4 * 4096

typedef __attribute__((ext_vector_type(4))) float f32x4;
typedef __bf16 bf16x8 __attribute__((ext_vector_type(8)));

#define GLDS(g, l)                                                        \
  __builtin_amdgcn_global_load_lds(                                       \
      (const __attribute__((address_space(1))) void*)(const void*)(g),    \
      (__attribute__((address_space(3))) void*)(void*)(l), 16, 0, 0)

// ---------------- prep: fp32 -> bf16 cast, 8 elems/thread ----------------
__global__ __launch_bounds__(256) void cast_bf16_kernel(
    const float* __restrict__ in, __bf16* __restrict__ out, int n8) {
  int i = blockIdx.x * blockDim.x + threadIdx.x;
  if (i >= n8) return;
  const f32x4* p = (const f32x4*)(in + (size_t)i * 8);
  f32x4 a = p[0], b = p[1];
  bf16x8 o = {(__bf16)a[0], (__bf16)a[1], (__bf16)a[2], (__bf16)a[3],
              (__bf16)b[0], (__bf16)b[1], (__bf16)b[2], (__bf16)b[3]};
  *(bf16x8*)(out + (size_t)i * 8) = o;
}

// ------------- prep: MB [512][1024] -> MB^T [1024][512] via LDS ----------
__global__ __launch_bounds__(256) void transpose_mb_lds_kernel(
    const float* __restrict__ mb, __bf16* __restrict__ mbt) {
  __shared__ __bf16 tile[32][33];
  const int tx = threadIdx.x & 7, ty = threadIdx.x >> 3;  // 8 x 32
  const int w0 = (blockIdx.x & 15) * 32;   // 512/32 = 16
  const int d0 = (blockIdx.x >> 4) * 32;   // 1024/32 = 32 -> 512 blocks
  f32x4 v = *(const f32x4*)(mb + (size_t)(w0 + ty) * EMBED + d0 + tx * 4);
#pragma unroll
  for (int j = 0; j < 4; ++j) tile[tx * 4 + j][ty] = (__bf16)v[j];
  __syncthreads();
  unsigned u0 =
      ((unsigned)__builtin_bit_cast(unsigned short, tile[ty][tx * 4 + 1]) << 16) |
      (unsigned)__builtin_bit_cast(unsigned short, tile[ty][tx * 4 + 0]);
  unsigned u1 =
      ((unsigned)__builtin_bit_cast(unsigned short, tile[ty][tx * 4 + 3]) << 16) |
      (unsigned)__builtin_bit_cast(unsigned short, tile[ty][tx * 4 + 2]);
  uint2 w2 = {u0, u1};
  *(uint2*)(mbt + (size_t)(d0 + ty) * WINDOW + w0 + tx * 4) = w2;
}

// ============== scores + softmax + x-cast mega kernel (B-direct) =========
// B fragments load straight from L2 (mbb is 1MB, L2-resident) into regs —
// no ldsB, no glds, no explicit vmcnt. A stays reg-staged (f32 load ->
// bf16 pack -> ds_write + xb store byproduct), ring-3 LDS, 1 barrier/tile.
__global__ __launch_bounds__(512, 1) void scores_mega_kernel(
    const float* __restrict__ x, const __bf16* __restrict__ mbb,
    __bf16* __restrict__ xb, __bf16* __restrict__ s1) {
  __shared__ __align__(16) __bf16 ldsA[3][64 * 32];   // 12 KB
  __shared__ float sred[8][64];                       // 2 KB
  __shared__ float sfin[64];
  const int tid = threadIdx.x, lane = tid & 63, wave = tid >> 6;
  const int row0 = blockIdx.x * 64;  // grid 256
  const int warp_n = wave;           // cols wave*64..+63
  const int fr = lane & 15, fq = lane >> 4;

  // A reg-stage map: thread -> row tid>>3, 4 f32 at col (tid&7)*4
  const int arow = tid >> 3;
  const int ag = (tid >> 1) & 3;  // granule
  const int ah = tid & 1;         // half within granule
  const int fA = (arow & 3) ^ ((arow >> 2) & 3);
  const int aws = arow * 32 + ((ag ^ fA) * 8) + ah * 4;
  const float* aSrc = x + (size_t)(row0 + arow) * EMBED + (tid & 7) * 4;
  __bf16* xbDst = xb + (size_t)(row0 + arow) * EMBED + (tid & 7) * 4;

  // B per-lane base: frag n = mbb row (warp_n*64 + n*16 + fr), k fq*8
  const __bf16* bP = mbb + (size_t)(warp_n * 64 + fr) * EMBED + fq * 8;

#define PACK_WRITE(av, buf, t)                                                \
  {                                                                           \
    unsigned u0 =                                                             \
        ((unsigned)__builtin_bit_cast(unsigned short, (__bf16)av[1]) << 16) | \
        (unsigned)__builtin_bit_cast(unsigned short, (__bf16)av[0]);          \
    unsigned u1 =                                                             \
        ((unsigned)__builtin_bit_cast(unsigned short, (__bf16)av[3]) << 16) | \
        (unsigned)__builtin_bit_cast(unsigned short, (__bf16)av[2]);          \
    uint2 w2 = {u0, u1};                                                      \
    *(uint2*)(&ldsA[buf][aws]) = w2;                                          \
    *(uint2*)(xbDst + (t) * 32) = w2;                                         \
  }

#define MCOMPUTE(cur, t)                                                      \
  {                                                                           \
    const __bf16* As_ = &ldsA[cur][0];                                        \
    const int pg_ = (fq ^ ((fr & 3) ^ ((fr >> 2) & 3))) * 8;                  \
    bf16x8 af[4], bfv[4];                                                     \
    _Pragma("unroll") for (int n = 0; n < 4; ++n)                             \
        bfv[n] = *(const bf16x8*)(bP + (size_t)(n * 16) * EMBED + (t) * 32);  \
    _Pragma("unroll") for (int m = 0; m < 4; ++m)                             \
        af[m] = *(const bf16x8*)(As_ + (m * 16 + fr) * 32 + pg_);             \
    __builtin_amdgcn_s_setprio(1);                                            \
    _Pragma("unroll") for (int m = 0; m < 4; ++m)                             \
        _Pragma("unroll") for (int n = 0; n < 4; ++n)                         \
            acc[m][n] = __builtin_amdgcn_mfma_f32_16x16x32_bf16(              \
                af[m], bfv[n], acc[m][n], 0, 0, 0);                           \
    __builtin_amdgcn_s_setprio(0);                                            \
  }

// One tile. APACK = A(t+1) regs (packed here); ALOAD = A(t+2) regs.
#define TBODY(t, APACK, ALOAD)                                                \
  {                                                                           \
    if ((t) + 2 < 32) ALOAD = *(const f32x4*)(aSrc + ((t) + 2) * 32);         \
    MCOMPUTE(rs0, t);                                                         \
    if ((t) + 1 < 32) PACK_WRITE(APACK, rs1, (t) + 1);                        \
    asm volatile("s_waitcnt lgkmcnt(0)" ::: "memory");                        \
    __builtin_amdgcn_s_barrier();                                             \
    const int tmp_ = rs0; rs0 = rs1; rs1 = rs2; rs2 = tmp_;                   \
  }

  f32x4 acc[4][4];
#pragma unroll
  for (int m = 0; m < 4; ++m)
#pragma unroll
    for (int n = 0; n < 4; ++n) acc[m][n] = (f32x4){0.f, 0.f, 0.f, 0.f};

  int rs0 = 0, rs1 = 1, rs2 = 2;
  f32x4 aE, aO;
  // prologue: A(0) pack into slot 0; A(1) into regs
  {
    f32x4 a0 = *(const f32x4*)(aSrc);
    aO = *(const f32x4*)(aSrc + 32);
    PACK_WRITE(a0, 0, 0);
    asm volatile("s_waitcnt lgkmcnt(0)" ::: "memory");
    __builtin_amdgcn_s_barrier();
  }

  for (int t = 0; t < 32; t += 2) {
    TBODY(t, aO, aE);
    TBODY(t + 1, aE, aO);
  }
#undef TBODY
#undef PACK_WRITE
#undef MCOMPUTE

  // -------- softmax epilogue (full 512-col rows in block) ----------------
  const float scale = 0.03125f;  // 1/sqrt(1024)
  float rmx[4][4];
#pragma unroll
  for (int m = 0; m < 4; ++m)
#pragma unroll
    for (int j = 0; j < 4; ++j) {
      float v = -1e30f;
#pragma unroll
      for (int n = 0; n < 4; ++n) {
        acc[m][n][j] *= scale;
        v = fmaxf(v, acc[m][n][j]);
      }
      rmx[m][j] = v;
    }
#pragma unroll
  for (int off = 1; off < 16; off <<= 1)
#pragma unroll
    for (int m = 0; m < 4; ++m)
#pragma unroll
      for (int j = 0; j < 4; ++j)
        rmx[m][j] = fmaxf(rmx[m][j], __shfl_xor(rmx[m][j], off));
  if (fr == 0) {
#pragma unroll
    for (int m = 0; m < 4; ++m)
#pragma unroll
      for (int j = 0; j < 4; ++j) sred[warp_n][m * 16 + fq * 4 + j] = rmx[m][j];
  }
  __syncthreads();
  if (tid < 64) {
    float v = sred[0][tid];
#pragma unroll
    for (int w = 1; w < 8; ++w) v = fmaxf(v, sred[w][tid]);
    sfin[tid] = v;
  }
  __syncthreads();

  float rsm[4][4];
#pragma unroll
  for (int m = 0; m < 4; ++m)
#pragma unroll
    for (int j = 0; j < 4; ++j) {
      const float fm = sfin[m * 16 + fq * 4 + j];
      float s = 0.f;
#pragma unroll
      for (int n = 0; n < 4; ++n) {
        float e = __expf(acc[m][n][j] - fm);
        acc[m][n][j] = e;
        s += e;
      }
      rsm[m][j] = s;
    }
#pragma unroll
  for (int off = 1; off < 16; off <<= 1)
#pragma unroll
    for (int m = 0; m < 4; ++m)
#pragma unroll
      for (int j = 0; j < 4; ++j) rsm[m][j] += __shfl_xor(rsm[m][j], off);
  if (fr == 0) {
#pragma unroll
    for (int m = 0; m < 4; ++m)
#pragma unroll
      for (int j = 0; j < 4; ++j) sred[warp_n][m * 16 + fq * 4 + j] = rsm[m][j];
  }
  __syncthreads();
  if (tid < 64) {
    float v = sred[0][tid];
#pragma unroll
    for (int w = 1; w < 8; ++w) v += sred[w][tid];
    sfin[tid] = 1.0f / v;
  }
  __syncthreads();

#pragma unroll
  for (int m = 0; m < 4; ++m)
#pragma unroll
    for (int j = 0; j < 4; ++j) {
      const int row = row0 + m * 16 + fq * 4 + j;
      const float inv = sfin[m * 16 + fq * 4 + j];
#pragma unroll
      for (int n = 0; n < 4; ++n)
        s1[(size_t)row * WINDOW + warp_n * 64 + n * 16 + fr] =
            (__bf16)(acc[m][n][j] * inv);
    }
}

// ===== fused dual GEMM + blend, B-direct: A ring-3 LDS, 1 barrier/tile ===
// B fragments read straight from L2 (mbt 1MB + gwb 2MB, L2-resident per
// XCD) into registers — halves LDS-pipe traffic and barrier count.
// Ordering: B loads issued BEFORE STG_A(vt+2) so the compiler's B-wait
// (in-order vmcnt) leaves the A-prefetch in flight.
// vt 0..7: retrieved (A=s1, B=mbt, K=512) -> accr
// vt 8..23: gate (A=xb, B=gwb, K=1024)    -> accg
__global__ __launch_bounds__(256) void dual_bdir_kernel(
    const __bf16* __restrict__ s1, const __bf16* __restrict__ xb,
    const __bf16* __restrict__ mbt, const __bf16* __restrict__ gwb,
    const float* __restrict__ gb, float* __restrict__ out) {
  __shared__ __align__(16) __bf16 ldsA[3][128 * 64];  // 48 KB
  const int tid = threadIdx.x, lane = tid & 63, wave = tid >> 6;
  const int bid = blockIdx.x;
  const int xcd = bid & 7;
  const int g = bid >> 3;                  // 0..127
  const int bm = xcd * 16 + (g >> 3);      // bn inner: A-panel L2 locality
  const int bn = g & 7;
  const int row0 = bm * 128, col0 = bn * 128;
  const int warp_m = wave >> 1, warp_n = wave & 1;  // 2x2 waves, 64x64 tiles
  const int fr = lane & 15, fq = lane >> 4;
  const int srow = lane >> 3;              // 0..7
  const int sgc = (lane & 7) ^ srow;       // pre-swizzled source granule
  const int wv32 = wave * 32;

  const __bf16* aR = s1 + (size_t)(row0 + wv32 + srow) * WINDOW + sgc * 8;
  const __bf16* aG = xb + (size_t)(row0 + wv32 + srow) * EMBED + sgc * 8;
  // per-lane B base pointers (direct, no swizzle needed)
  const __bf16* bRp = mbt + (size_t)(col0 + warp_n * 64 + fr) * WINDOW + fq * 8;
  const __bf16* bGp = gwb + (size_t)(col0 + warp_n * 64 + fr) * EMBED + fq * 8;

#define STG_A(vt, slot)                                                       \
  {                                                                           \
    if ((vt) < 8) {                                                           \
      const int k0_ = (vt)*64;                                                \
      _Pragma("unroll") for (int c = 0; c < 4; ++c)                           \
          GLDS(aR + (size_t)c * 8 * WINDOW + k0_,                             \
               &ldsA[slot][(wv32 + c * 8) * 64]);                             \
    } else {                                                                  \
      const int k0_ = ((vt)-8) * 64;                                          \
      _Pragma("unroll") for (int c = 0; c < 4; ++c)                           \
          GLDS(aG + (size_t)c * 8 * EMBED + k0_,                              \
               &ldsA[slot][(wv32 + c * 8) * 64]);                             \
    }                                                                         \
  }

#define DTILE(ACC, vt, BP, LDB_, KB)                                          \
  {                                                                           \
    if ((vt) < 23) {                                                          \
      asm volatile("s_waitcnt vmcnt(4)" ::: "memory");                        \
    } else {                                                                  \
      asm volatile("s_waitcnt vmcnt(0)" ::: "memory");                        \
    }                                                                         \
    __builtin_amdgcn_s_barrier();                                             \
    bf16x8 b0[4], b1[4];                                                      \
    _Pragma("unroll") for (int n = 0; n < 4; ++n) {                           \
      b0[n] = *(const bf16x8*)(BP + (size_t)(n * 16) * LDB_ + (KB));          \
      b1[n] = *(const bf16x8*)(BP + (size_t)(n * 16) * LDB_ + (KB) + 32);     \
    }                                                                         \
    if ((vt) + 2 < 24) STG_A((vt) + 2, ((vt) + 2) % 3);                       \
    const __bf16* As_ = &ldsA[(vt) % 3][(warp_m * 64 + fr) * 64];             \
    bf16x8 af[4];                                                             \
    _Pragma("unroll") for (int m = 0; m < 4; ++m)                             \
        af[m] = *(const bf16x8*)(As_ + m * 16 * 64 + ((fq ^ (fr & 7)) * 8));  \
    __builtin_amdgcn_s_setprio(1);                                            \
    _Pragma("unroll") for (int m = 0; m < 4; ++m)                             \
        _Pragma("unroll") for (int n = 0; n < 4; ++n)                         \
            ACC[m][n] = __builtin_amdgcn_mfma_f32_16x16x32_bf16(              \
                af[m], b0[n], ACC[m][n], 0, 0, 0);                            \
    __builtin_amdgcn_s_setprio(0);                                            \
    _Pragma("unroll") for (int m = 0; m < 4; ++m)                             \
        af[m] = *(const bf16x8*)(As_ + m * 16 * 64 +                          \
                                 (((4 + fq) ^ (fr & 7)) * 8));                \
    __builtin_amdgcn_s_setprio(1);                                            \
    _Pragma("unroll") for (int m = 0; m < 4; ++m)                             \
        _Pragma("unroll") for (int n = 0; n < 4; ++n)                         \
            ACC[m][n] = __builtin_amdgcn_mfma_f32_16x16x32_bf16(              \
                af[m], b1[n], ACC[m][n], 0, 0, 0);                            \
    __builtin_amdgcn_s_setprio(0);                                            \
  }

  f32x4 accr[4][4], accg[4][4];
#pragma unroll
  for (int m = 0; m < 4; ++m)
#pragma unroll
    for (int n = 0; n < 4; ++n) {
      accr[m][n] = (f32x4){0.f, 0.f, 0.f, 0.f};
      accg[m][n] = (f32x4){0.f, 0.f, 0.f, 0.f};
    }

  STG_A(0, 0);
  STG_A(1, 1);

  for (int vt = 0; vt < 8; ++vt) {
    DTILE(accr, vt, bRp, WINDOW, vt * 64);
  }
  for (int vt = 8; vt < 24; ++vt) {
    DTILE(accg, vt, bGp, EMBED, (vt - 8) * 64);
  }
#undef DTILE
#undef STG_A

  // epilogue: g = sigmoid(accg + gb); out = g*x + (1-g)*accr
#pragma unroll
  for (int n = 0; n < 4; ++n) {
    const int col = col0 + warp_n * 64 + n * 16 + fr;
    const float bias = gb[col];
#pragma unroll
    for (int m = 0; m < 4; ++m) {
#pragma unroll
      for (int j = 0; j < 4; ++j) {
        const int row = row0 + warp_m * 64 + m * 16 + fq * 4 + j;
        const size_t o = (size_t)row * EMBED + col;
        const float gt = 1.0f / (1.0f + __expf(-(accg[m][n][j] + bias)));
        const float xv = (float)xb[o];
        out[o] = gt * xv + (1.0f - gt) * accr[m][n][j];
      }
    }
  }
}

extern "C" void kernel_launch(void* const* d_in, const int* in_sizes, int n_in,
                              void* d_out, int out_size, void* d_ws,
                              size_t ws_size, hipStream_t stream) {
  const float* x = (const float*)d_in[0];
  const float* mb = (const float*)d_in[1];
  const float* gw = (const float*)d_in[2];
  const float* gb = (const float*)d_in[3];
  float* out = (float*)d_out;

  char* ws = (char*)d_ws;
  __bf16* xb = (__bf16*)(ws);                   // 16384*1024*2 = 33,554,432
  __bf16* mbb = (__bf16*)(ws + 33554432);       // 512*1024*2  =  1,048,576
  __bf16* mbt = (__bf16*)(ws + 34603008);       // 1024*512*2  =  1,048,576
  __bf16* gwb = (__bf16*)(ws + 35651584);       // 1024*1024*2 =  2,097,152
  __bf16* s1 = (__bf16*)(ws + 37748736);        // 16384*512*2 = 16,777,216
  // total 54,525,952 bytes

  cast_bf16_kernel<<<256, 256, 0, stream>>>(mb, mbb, 65536);
  cast_bf16_kernel<<<512, 256, 0, stream>>>(gw, gwb, 131072);
  transpose_mb_lds_kernel<<<512, 256, 0, stream>>>(mb, mbt);
  // scores + softmax + x-cast fused (writes xb and normalized s1)
  scores_mega_kernel<<<256, 512, 0, stream>>>(x, mbb, xb, s1);
  dual_bdir_kernel<<<1024, 256, 0, stream>>>(s1, xb, mbt, gwb, gb, out);
}

// Round 17
// 117.071 us; speedup vs baseline: 1.5664x; 1.5664x over previous
//
#include <hip/hip_runtime.h>
#include <hip/hip_bf16.h>

#define EMBED 1024
#define WINDOW 512
#define NROWS 16384  // 4 * 4096

typedef __attribute__((ext_vector_type(4))) float f32x4;
typedef __bf16 bf16x8 __attribute__((ext_vector_type(8)));

#define GLDS(g, l)                                                        \
  __builtin_amdgcn_global_load_lds(                                       \
      (const __attribute__((address_space(1))) void*)(const void*)(g),    \
      (__attribute__((address_space(3))) void*)(void*)(l), 16, 0, 0)

// ---------------- prep: fp32 -> bf16 cast, 8 elems/thread ----------------
__global__ __launch_bounds__(256) void cast_bf16_kernel(
    const float* __restrict__ in, __bf16* __restrict__ out, int n8) {
  int i = blockIdx.x * blockDim.x + threadIdx.x;
  if (i >= n8) return;
  const f32x4* p = (const f32x4*)(in + (size_t)i * 8);
  f32x4 a = p[0], b = p[1];
  bf16x8 o = {(__bf16)a[0], (__bf16)a[1], (__bf16)a[2], (__bf16)a[3],
              (__bf16)b[0], (__bf16)b[1], (__bf16)b[2], (__bf16)b[3]};
  *(bf16x8*)(out + (size_t)i * 8) = o;
}

// ------------- prep: MB [512][1024] -> MB^T [1024][512] via LDS ----------
__global__ __launch_bounds__(256) void transpose_mb_lds_kernel(
    const float* __restrict__ mb, __bf16* __restrict__ mbt) {
  __shared__ __bf16 tile[32][33];
  const int tx = threadIdx.x & 7, ty = threadIdx.x >> 3;  // 8 x 32
  const int w0 = (blockIdx.x & 15) * 32;   // 512/32 = 16
  const int d0 = (blockIdx.x >> 4) * 32;   // 1024/32 = 32 -> 512 blocks
  f32x4 v = *(const f32x4*)(mb + (size_t)(w0 + ty) * EMBED + d0 + tx * 4);
#pragma unroll
  for (int j = 0; j < 4; ++j) tile[tx * 4 + j][ty] = (__bf16)v[j];
  __syncthreads();
  unsigned u0 =
      ((unsigned)__builtin_bit_cast(unsigned short, tile[ty][tx * 4 + 1]) << 16) |
      (unsigned)__builtin_bit_cast(unsigned short, tile[ty][tx * 4 + 0]);
  unsigned u1 =
      ((unsigned)__builtin_bit_cast(unsigned short, tile[ty][tx * 4 + 3]) << 16) |
      (unsigned)__builtin_bit_cast(unsigned short, tile[ty][tx * 4 + 2]);
  uint2 w2 = {u0, u1};
  *(uint2*)(mbt + (size_t)(d0 + ty) * WINDOW + w0 + tx * 4) = w2;
}

// ---------------- softmax in-place on S1 rows (512 wide) -----------------
__global__ __launch_bounds__(256) void softmax_kernel(__bf16* __restrict__ s1) {
  const int row = blockIdx.x * 4 + (threadIdx.x >> 6);
  const int lane = threadIdx.x & 63;
  __bf16* p = s1 + (size_t)row * WINDOW + lane * 8;
  bf16x8 v = *(const bf16x8*)p;
  float f[8];
  float mx = -1e30f;
#pragma unroll
  for (int j = 0; j < 8; ++j) {
    f[j] = (float)v[j] * 0.03125f;  // 1/sqrt(1024)
    mx = fmaxf(mx, f[j]);
  }
#pragma unroll
  for (int off = 1; off < 64; off <<= 1) mx = fmaxf(mx, __shfl_xor(mx, off));
  float s = 0.f;
#pragma unroll
  for (int j = 0; j < 8; ++j) {
    f[j] = __expf(f[j] - mx);
    s += f[j];
  }
#pragma unroll
  for (int off = 1; off < 64; off <<= 1) s += __shfl_xor(s, off);
  const float inv = 1.0f / s;
  bf16x8 o;
#pragma unroll
  for (int j = 0; j < 8; ++j) o[j] = (__bf16)(f[j] * inv);
  *(bf16x8*)p = o;
}

// ---------------- scores kernel (R5 structure, known-good) ---------------
#define SLOADFRAGS(cb, kk)                                                    \
  {                                                                           \
    const __bf16* As_ = &ldsA[cb][(warp_m * 64 + fr) * 64];                   \
    const __bf16* Bs_ = &ldsB[cb][(warp_n * 64 + fr) * 64];                   \
    const int pg_ = (((kk)*4 + fq) ^ (fr & 7)) * 8;                           \
    _Pragma("unroll") for (int m = 0; m < 4; ++m)                             \
        af[m] = *(const bf16x8*)(As_ + m * 16 * 64 + pg_);                    \
    _Pragma("unroll") for (int n = 0; n < 4; ++n)                             \
        bfv[n] = *(const bf16x8*)(Bs_ + n * 16 * 64 + pg_);                   \
  }

#define SMFMA16(ACC)                                                          \
  {                                                                           \
    __builtin_amdgcn_s_barrier();                                             \
    asm volatile("s_waitcnt lgkmcnt(0)" ::: "memory");                        \
    __builtin_amdgcn_s_setprio(1);                                            \
    _Pragma("unroll") for (int m = 0; m < 4; ++m)                             \
        _Pragma("unroll") for (int n = 0; n < 4; ++n)                         \
            ACC[m][n] = __builtin_amdgcn_mfma_f32_16x16x32_bf16(              \
                af[m], bfv[n], ACC[m][n], 0, 0, 0);                           \
    __builtin_amdgcn_s_setprio(0);                                            \
    __builtin_amdgcn_s_barrier();                                             \
  }

__global__ __launch_bounds__(512, 2) void gemm_scores_kernel(
    const __bf16* __restrict__ xb, const __bf16* __restrict__ mbb,
    __bf16* __restrict__ s1) {
  __shared__ __align__(16) __bf16 ldsA[3][256 * 64];
  __shared__ __align__(16) __bf16 ldsB[3][128 * 64];
  const int tid = threadIdx.x;
  const int lane = tid & 63;
  const int wave = tid >> 6;
  const int bid = blockIdx.x;            // 256 blocks
  const int xcd = bid & 7;
  const int idx = bid >> 3;              // 0..31
  const int bm = xcd * 8 + (idx & 7);    // 0..63
  const int bn = idx >> 3;               // 0..3
  const int row0 = bm * 256;
  const int col0 = bn * 128;
  const int warp_m = wave >> 1;
  const int warp_n = wave & 1;
  const int srow = lane >> 3;
  const int sgc = (lane & 7) ^ srow;
  const int wv32 = wave * 32;
  const int wv16 = wave * 16;
  const int fr = lane & 15;
  const int fq = lane >> 4;

  const __bf16* aS = xb + (size_t)(row0 + wv32 + srow) * EMBED + sgc * 8;
  const __bf16* bS = mbb + (size_t)(col0 + wv16 + srow) * EMBED + sgc * 8;

#define STAGE_S1(vt, buf)                                                     \
  {                                                                           \
    const int k0_ = (vt)*64;                                                  \
    _Pragma("unroll") for (int c = 0; c < 2; ++c)                             \
        GLDS(aS + (size_t)c * 8 * EMBED + k0_, &ldsA[buf][(wv32 + c * 8) * 64]); \
    GLDS(bS + k0_, &ldsB[buf][wv16 * 64]);                                    \
  }
#define STAGE_S2(vt, buf)                                                     \
  {                                                                           \
    const int k0_ = (vt)*64;                                                  \
    _Pragma("unroll") for (int c = 2; c < 4; ++c)                             \
        GLDS(aS + (size_t)c * 8 * EMBED + k0_, &ldsA[buf][(wv32 + c * 8) * 64]); \
    GLDS(bS + (size_t)8 * EMBED + k0_, &ldsB[buf][(wv16 + 8) * 64]);          \
  }

  f32x4 acc[4][4];
#pragma unroll
  for (int m = 0; m < 4; ++m)
#pragma unroll
    for (int n = 0; n < 4; ++n) acc[m][n] = (f32x4){0.f, 0.f, 0.f, 0.f};
  bf16x8 af[4], bfv[4];

  STAGE_S1(0, 0); STAGE_S2(0, 0);
  STAGE_S1(1, 1); STAGE_S2(1, 1);
  asm volatile("s_waitcnt vmcnt(6)" ::: "memory");
  __builtin_amdgcn_s_barrier();

  const int NT = 16;
  for (int vt = 0; vt < NT; ++vt) {
    const int cb = vt % 3;
    const int nb = (vt + 2) % 3;
    SLOADFRAGS(cb, 0);
    if (vt + 2 < NT) STAGE_S1(vt + 2, nb);
    SMFMA16(acc);
    SLOADFRAGS(cb, 1);
    if (vt + 2 < NT) STAGE_S2(vt + 2, nb);
    if (vt < NT - 2) {
      asm volatile("s_waitcnt vmcnt(6)" ::: "memory");
    } else if (vt == NT - 2) {
      asm volatile("s_waitcnt vmcnt(0)" ::: "memory");
    }
    SMFMA16(acc);
  }
#undef STAGE_S1
#undef STAGE_S2

#pragma unroll
  for (int n = 0; n < 4; ++n) {
    const int col = col0 + warp_n * 64 + n * 16 + fr;
#pragma unroll
    for (int m = 0; m < 4; ++m)
#pragma unroll
      for (int j = 0; j < 4; ++j) {
        const int row = row0 + warp_m * 64 + m * 16 + fq * 4 + j;
        s1[(size_t)row * WINDOW + col] = (__bf16)acc[m][n][j];
      }
  }
}

// ======= fused dual GEMM + blend: 4 waves, 128x128, dbuf, 2 blocks/CU ====
// R11's proven kernel verbatim (73 us, MfmaUtil 28%, 0 conflicts):
// BK=64 dbuf, STG -> vmcnt(8) -> bar -> COMPUTE -> bar; 128B-row layout
// with 8-granule involution; bn-inner bijection for A-panel L2 locality.
__global__ __launch_bounds__(256, 2) void dual_fused128_kernel(
    const __bf16* __restrict__ s1, const __bf16* __restrict__ xb,
    const __bf16* __restrict__ mbt, const __bf16* __restrict__ gwb,
    const float* __restrict__ gb, float* __restrict__ out) {
  __shared__ __align__(16) __bf16 ldsA[2][128 * 64];  // 32 KB
  __shared__ __align__(16) __bf16 ldsB[2][128 * 64];  // 32 KB
  const int tid = threadIdx.x, lane = tid & 63, wave = tid >> 6;
  const int bid = blockIdx.x;
  const int xcd = bid & 7;
  const int g = bid >> 3;                  // 0..127
  const int bm = xcd * 16 + (g >> 3);      // bn inner: A-panel L2 locality
  const int bn = g & 7;
  const int row0 = bm * 128, col0 = bn * 128;
  const int warp_m = wave >> 1, warp_n = wave & 1;  // 2x2 waves, 64x64 tiles
  const int fr = lane & 15, fq = lane >> 4;
  const int srow = lane >> 3;              // 0..7
  const int sgc = (lane & 7) ^ srow;       // pre-swizzled source granule
  const int wv32 = wave * 32;

  const __bf16* aR = s1 + (size_t)(row0 + wv32 + srow) * WINDOW + sgc * 8;
  const __bf16* bR = mbt + (size_t)(col0 + wv32 + srow) * WINDOW + sgc * 8;
  const __bf16* aG = xb + (size_t)(row0 + wv32 + srow) * EMBED + sgc * 8;
  const __bf16* bG = gwb + (size_t)(col0 + wv32 + srow) * EMBED + sgc * 8;

#define STG(vt, buf)                                                          \
  {                                                                           \
    if ((vt) < 8) {                                                           \
      const int k0_ = (vt)*64;                                                \
      _Pragma("unroll") for (int c = 0; c < 4; ++c)                           \
          GLDS(aR + (size_t)c * 8 * WINDOW + k0_,                             \
               &ldsA[buf][(wv32 + c * 8) * 64]);                              \
      _Pragma("unroll") for (int c = 0; c < 4; ++c)                           \
          GLDS(bR + (size_t)c * 8 * WINDOW + k0_,                             \
               &ldsB[buf][(wv32 + c * 8) * 64]);                              \
    } else {                                                                  \
      const int k0_ = ((vt)-8) * 64;                                          \
      _Pragma("unroll") for (int c = 0; c < 4; ++c)                           \
          GLDS(aG + (size_t)c * 8 * EMBED + k0_,                              \
               &ldsA[buf][(wv32 + c * 8) * 64]);                              \
      _Pragma("unroll") for (int c = 0; c < 4; ++c)                           \
          GLDS(bG + (size_t)c * 8 * EMBED + k0_,                              \
               &ldsB[buf][(wv32 + c * 8) * 64]);                              \
    }                                                                         \
  }

#define BARF                                                                  \
  {                                                                           \
    asm volatile("" ::: "memory");                                            \
    __builtin_amdgcn_s_barrier();                                             \
    asm volatile("" ::: "memory");                                            \
  }

#define COMPUTE(ACC, cur)                                                     \
  {                                                                           \
    const __bf16* As_ = &ldsA[cur][(warp_m * 64 + fr) * 64];                  \
    const __bf16* Bs_ = &ldsB[cur][(warp_n * 64 + fr) * 64];                  \
    _Pragma("unroll") for (int kk = 0; kk < 2; ++kk) {                        \
      const int pg_ = ((kk * 4 + fq) ^ (fr & 7)) * 8;                         \
      bf16x8 af[4], bfv[4];                                                   \
      _Pragma("unroll") for (int m = 0; m < 4; ++m)                           \
          af[m] = *(const bf16x8*)(As_ + m * 16 * 64 + pg_);                  \
      _Pragma("unroll") for (int n = 0; n < 4; ++n)                           \
          bfv[n] = *(const bf16x8*)(Bs_ + n * 16 * 64 + pg_);                 \
      __builtin_amdgcn_s_setprio(1);                                          \
      _Pragma("unroll") for (int m = 0; m < 4; ++m)                           \
          _Pragma("unroll") for (int n = 0; n < 4; ++n)                       \
              ACC[m][n] = __builtin_amdgcn_mfma_f32_16x16x32_bf16(            \
                  af[m], bfv[n], ACC[m][n], 0, 0, 0);                         \
      __builtin_amdgcn_s_setprio(0);                                          \
    }                                                                         \
  }

  f32x4 accr[4][4], accg[4][4];
#pragma unroll
  for (int m = 0; m < 4; ++m)
#pragma unroll
    for (int n = 0; n < 4; ++n) {
      accr[m][n] = (f32x4){0.f, 0.f, 0.f, 0.f};
      accg[m][n] = (f32x4){0.f, 0.f, 0.f, 0.f};
    }

  STG(0, 0);
  for (int vt = 0; vt < 8; ++vt) {
    const int cur = vt & 1;
    STG(vt + 1, cur ^ 1);
    asm volatile("s_waitcnt vmcnt(8)" ::: "memory");
    BARF;
    COMPUTE(accr, cur);
    BARF;
  }
  for (int vt = 8; vt < 24; ++vt) {
    const int cur = vt & 1;
    if (vt + 1 < 24) {
      STG(vt + 1, cur ^ 1);
      asm volatile("s_waitcnt vmcnt(8)" ::: "memory");
    } else {
      asm volatile("s_waitcnt vmcnt(0)" ::: "memory");
    }
    BARF;
    COMPUTE(accg, cur);
    BARF;
  }
#undef STG
#undef COMPUTE
#undef BARF

#pragma unroll
  for (int n = 0; n < 4; ++n) {
    const int col = col0 + warp_n * 64 + n * 16 + fr;
    const float bias = gb[col];
#pragma unroll
    for (int m = 0; m < 4; ++m) {
#pragma unroll
      for (int j = 0; j < 4; ++j) {
        const int row = row0 + warp_m * 64 + m * 16 + fq * 4 + j;
        const size_t o = (size_t)row * EMBED + col;
        const float gt = 1.0f / (1.0f + __expf(-(accg[m][n][j] + bias)));
        const float xv = (float)xb[o];
        out[o] = gt * xv + (1.0f - gt) * accr[m][n][j];
      }
    }
  }
}

extern "C" void kernel_launch(void* const* d_in, const int* in_sizes, int n_in,
                              void* d_out, int out_size, void* d_ws,
                              size_t ws_size, hipStream_t stream) {
  const float* x = (const float*)d_in[0];
  const float* mb = (const float*)d_in[1];
  const float* gw = (const float*)d_in[2];
  const float* gb = (const float*)d_in[3];
  float* out = (float*)d_out;

  char* ws = (char*)d_ws;
  __bf16* xb = (__bf16*)(ws);                   // 16384*1024*2 = 33,554,432
  __bf16* mbb = (__bf16*)(ws + 33554432);       // 512*1024*2  =  1,048,576
  __bf16* mbt = (__bf16*)(ws + 34603008);       // 1024*512*2  =  1,048,576
  __bf16* gwb = (__bf16*)(ws + 35651584);       // 1024*1024*2 =  2,097,152
  __bf16* s1 = (__bf16*)(ws + 37748736);        // 16384*512*2 = 16,777,216
  // total 54,525,952 bytes

  cast_bf16_kernel<<<8192, 256, 0, stream>>>(x, xb, 2097152);
  cast_bf16_kernel<<<256, 256, 0, stream>>>(mb, mbb, 65536);
  cast_bf16_kernel<<<512, 256, 0, stream>>>(gw, gwb, 131072);
  transpose_mb_lds_kernel<<<512, 256, 0, stream>>>(mb, mbt);
  gemm_scores_kernel<<<256, 512, 0, stream>>>(xb, mbb, s1);
  softmax_kernel<<<4096, 256, 0, stream>>>(s1);
  dual_fused128_kernel<<<1024, 256, 0, stream>>>(s1, xb, mbt, gwb, gb, out);
}